// Round 4
// baseline (688.624 us; speedup 1.0000x reference)
//
#include <hip/hip_runtime.h>
#include <stdint.h>

#define N_NODES 100000
#define N_EDGES 3200000
#define N_BKT 782          // ceil(100000/128)
#define BKT_SHIFT 7
#define BKT_SIZE 128
#define CHUNK 4096
#define STAGE_CAP 4608     // 8 sigma above mean bucket size 4096

typedef unsigned int u32;
typedef unsigned short u16;
typedef short short8 __attribute__((ext_vector_type(8)));
typedef float f32x4 __attribute__((ext_vector_type(4)));

__device__ __forceinline__ u16 f32_bf16(float f) {
  u32 u = __float_as_uint(f);
  u += 0x7fffu + ((u >> 16) & 1u);   // RNE
  return (u16)(u >> 16);
}
__device__ __forceinline__ float bf_lo(u32 p) { return __uint_as_float(p << 16); }
__device__ __forceinline__ float bf_hi(u32 p) { return __uint_as_float(p & 0xffff0000u); }

#define GLOAD_LDS16(g, l)                                                  \
  __builtin_amdgcn_global_load_lds(                                        \
      (const __attribute__((address_space(1))) void*)(g),                  \
      (__attribute__((address_space(3))) void*)(l), 16, 0, 0)

// ---------------- bucket histogram ----------------

__global__ __launch_bounds__(1024) void k_zero2(int* ghist) {
  ghist[threadIdx.x] = 0;
}

__global__ __launch_bounds__(256) void k_hist(const int* __restrict__ eid,
                                              int* __restrict__ ghist) {
  __shared__ int hh[1024];
  int t = threadIdx.x;
  for (int b = t; b < 1024; b += 256) hh[b] = 0;
  __syncthreads();
  int base = blockIdx.x * CHUNK;
#pragma unroll
  for (int k = 0; k < 16; ++k) {
    int e = base + t + 256 * k;
    if (e < N_EDGES) atomicAdd(&hh[eid[e] >> BKT_SHIFT], 1);
  }
  __syncthreads();
  for (int b = t; b < 1024; b += 256) {
    int c = hh[b];
    if (c) atomicAdd(&ghist[b], c);
  }
}

// single-block scan of bucket counts -> bucket bases + cursors
__global__ __launch_bounds__(1024) void k_base(const int* __restrict__ ghist,
                                               int* __restrict__ bb,
                                               int* __restrict__ gcur) {
  __shared__ int sm[1024];
  int t = threadIdx.x;
  int v = (t < N_BKT) ? ghist[t] : 0;
  sm[t] = v;
  __syncthreads();
  for (int off = 1; off < 1024; off <<= 1) {
    int add = (t >= off) ? sm[t - off] : 0;
    __syncthreads();
    sm[t] += add;
    __syncthreads();
  }
  int ex = sm[t] - v;
  if (t < N_BKT) { bb[t] = ex; gcur[t] = ex; }
  if (t == 0) bb[N_BKT] = N_EDGES;
}

// ---------------- binning: block-local counting sort + coalesced flush -----
// entry pack: x = src | (dst&127)<<20 ; y = weight fp32
// binned[] ends up grouped by bucket (order within bucket arbitrary).

__global__ __launch_bounds__(256) void k_bin(const int* __restrict__ eis,
                                             const int* __restrict__ eid,
                                             const float* __restrict__ ew,
                                             int* __restrict__ gcur,
                                             uint2* __restrict__ binned) {
  __shared__ int cnt[1024];
  __shared__ int lstart[1024];
  __shared__ int delta[1024];
  __shared__ int lcur[1024];
  __shared__ int part[256];
  __shared__ uint2 stage[CHUNK];
  __shared__ u16 sbkt[CHUNK];
  int t = threadIdx.x;
  for (int b = t; b < 1024; b += 256) cnt[b] = 0;
  __syncthreads();
  int base = blockIdx.x * CHUNK;
  int cc = N_EDGES - base; if (cc > CHUNK) cc = CHUNK;
#pragma unroll
  for (int k = 0; k < 16; ++k) {
    int e = base + t + 256 * k;
    if (e < N_EDGES) atomicAdd(&cnt[eid[e] >> BKT_SHIFT], 1);
  }
  __syncthreads();
  int b4 = t * 4;
  int c0 = cnt[b4], c1 = cnt[b4 + 1], c2 = cnt[b4 + 2], c3 = cnt[b4 + 3];
  int bs = c0 + c1 + c2 + c3;
  part[t] = bs;
  __syncthreads();
  for (int off = 1; off < 256; off <<= 1) {
    int add = (t >= off) ? part[t - off] : 0;
    __syncthreads();
    part[t] += add;
    __syncthreads();
  }
  int ex = part[t] - bs;
  lstart[b4] = ex;                    lcur[b4] = ex;
  lstart[b4 + 1] = ex + c0;           lcur[b4 + 1] = ex + c0;
  lstart[b4 + 2] = ex + c0 + c1;      lcur[b4 + 2] = ex + c0 + c1;
  lstart[b4 + 3] = ex + c0 + c1 + c2; lcur[b4 + 3] = ex + c0 + c1 + c2;
  __syncthreads();
  for (int b = t; b < 1024; b += 256) {
    int c = cnt[b];
    if (c) {
      int g = atomicAdd(&gcur[b], c);
      delta[b] = g - lstart[b];
    }
  }
#pragma unroll
  for (int k = 0; k < 16; ++k) {
    int e = base + t + 256 * k;
    if (e < N_EDGES) {
      int dst = eid[e];
      int bkt = dst >> BKT_SHIFT;
      int pos = atomicAdd(&lcur[bkt], 1);
      stage[pos] = make_uint2((u32)eis[e] | ((u32)(dst & (BKT_SIZE - 1)) << 20),
                              __float_as_uint(ew[e]));
      sbkt[pos] = (u16)bkt;
    }
  }
  __syncthreads();
  for (int idx = t; idx < cc; idx += 256) {
    int bkt = sbkt[idx];
    binned[delta[bkt] + idx] = stage[idx];
  }
}

// ---------------- W1 transpose+convert: W1t[c][k] bf16 ----------------

__global__ void k_w1t(const float* __restrict__ W1, u16* __restrict__ w1t) {
  int i = blockIdx.x * 256 + threadIdx.x;  // i = c*512 + k
  if (i < 512 * 128) {
    int c = i >> 9, k = i & 511;
    w1t[i] = f32_bf16(W1[k * 128 + c]);
  }
}

// ---------------- GEMM1: support1[N][128] bf16 = x @ W1 (MFMA 16x16x32) ----
// 128x128 block tile, K_STEP=32, 4 waves (2x2 quadrants), double-buffered LDS,
// global_load_lds staging with source-swizzled addresses.

#define G1_NSTEP 16  // 512 / 32

__global__ __launch_bounds__(256) void k_gemm1(const float* __restrict__ x,
                                               const u16* __restrict__ w1t,
                                               u16* __restrict__ s1) {
  __shared__ __align__(16) u16 aS[2][128 * 32];    // 8 KB per buffer
  __shared__ __align__(16) float bS[2][128 * 32];  // 16 KB per buffer

  int t = threadIdx.x;
  int w = t >> 6, lane = t & 63;
  int wr = w >> 1, wc = w & 1;           // 2x2 wave quadrants (64 rows x 64 cols)
  int rbase = blockIdx.x * 128;

  // A staging: c = p>>6, q = (p>>4)&3 ; stored slot q holds data slot q^((c>>1)&3)
  int pA0 = ((0 * 4 + w) << 10) + lane * 16;
  int pA1 = ((1 * 4 + w) << 10) + lane * 16;
  int cA0 = pA0 >> 6, qA0 = (pA0 >> 4) & 3;
  int cA1 = pA1 >> 6, qA1 = (pA1 >> 4) & 3;
  int sA0 = qA0 ^ ((cA0 >> 1) & 3);
  int sA1 = qA1 ^ ((cA1 >> 1) & 3);
  const u16* gA0 = w1t + (size_t)cA0 * 512 + sA0 * 8;
  const u16* gA1 = w1t + (size_t)cA1 * 512 + sA1 * 8;

  // B staging: r = p>>7, q = (p>>4)&7 ; slot = q ^ (r&7)
  const float* gB[4];
#pragma unroll
  for (int j = 0; j < 4; ++j) {
    int p = ((j * 4 + w) << 10) + lane * 16;
    int r = p >> 7, q = (p >> 4) & 7;
    int slot = q ^ (r & 7);
    int rg = rbase + r;
    if (rg > N_NODES - 1) rg = N_NODES - 1;
    gB[j] = x + (size_t)rg * 512 + slot * 4;
  }

  int c_lane = lane & 15;
  int slotA = lane >> 4;
  int slotB = (lane >> 4) * 2;

  int aOff[4], bOffLo[4], bOffHi[4];
#pragma unroll
  for (int ci = 0; ci < 4; ++ci) {
    int c = wc * 64 + ci * 16 + c_lane;
    aOff[ci] = c * 64 + ((slotA ^ ((c >> 1) & 3)) << 4);
  }
#pragma unroll
  for (int ri = 0; ri < 4; ++ri) {
    int r = wr * 64 + ri * 16 + c_lane;
    int m = r & 7;
    bOffLo[ri] = r * 128 + ((slotB ^ m) << 4);
    bOffHi[ri] = r * 128 + (((slotB + 1) ^ m) << 4);
  }

  f32x4 acc[4][4] = {};

  {
    char* la = (char*)&aS[0][0];
    char* lb = (char*)&bS[0][0];
    GLOAD_LDS16(gA0, la + pA0 - lane * 16);
    GLOAD_LDS16(gA1, la + pA1 - lane * 16);
#pragma unroll
    for (int j = 0; j < 4; ++j)
      GLOAD_LDS16(gB[j], lb + ((j * 4 + w) << 10));
  }
  __syncthreads();

  int buf = 0;
#pragma unroll 1
  for (int s = 0; s < G1_NSTEP; ++s) {
    if (s + 1 < G1_NSTEP) {
      int kk = (s + 1) * 32;
      char* la = (char*)&aS[buf ^ 1][0];
      char* lb = (char*)&bS[buf ^ 1][0];
      GLOAD_LDS16(gA0 + kk, la + pA0 - lane * 16);
      GLOAD_LDS16(gA1 + kk, la + pA1 - lane * 16);
#pragma unroll
      for (int j = 0; j < 4; ++j)
        GLOAD_LDS16(gB[j] + kk, lb + ((j * 4 + w) << 10));
    }

    const char* la = (const char*)&aS[buf][0];
    const char* lb = (const char*)&bS[buf][0];
    short8 af[4];
#pragma unroll
    for (int ci = 0; ci < 4; ++ci)
      af[ci] = *(const short8*)(la + aOff[ci]);
#pragma unroll
    for (int ri = 0; ri < 4; ++ri) {
      f32x4 lo = *(const f32x4*)(lb + bOffLo[ri]);
      f32x4 hi = *(const f32x4*)(lb + bOffHi[ri]);
      short8 bf;
      bf[0] = (short)f32_bf16(lo[0]);
      bf[1] = (short)f32_bf16(lo[1]);
      bf[2] = (short)f32_bf16(lo[2]);
      bf[3] = (short)f32_bf16(lo[3]);
      bf[4] = (short)f32_bf16(hi[0]);
      bf[5] = (short)f32_bf16(hi[1]);
      bf[6] = (short)f32_bf16(hi[2]);
      bf[7] = (short)f32_bf16(hi[3]);
#pragma unroll
      for (int ci = 0; ci < 4; ++ci)
        acc[ri][ci] = __builtin_amdgcn_mfma_f32_16x16x32_bf16(af[ci], bf, acc[ri][ci], 0, 0, 0);
    }
    __syncthreads();
    buf ^= 1;
  }

  int kg = lane >> 4;
#pragma unroll
  for (int ri = 0; ri < 4; ++ri) {
    int xr = rbase + wr * 64 + ri * 16 + c_lane;
    if (xr < N_NODES) {
#pragma unroll
      for (int ci = 0; ci < 4; ++ci) {
        uint2 pk;
        pk.x = (u32)f32_bf16(acc[ri][ci][0]) | ((u32)f32_bf16(acc[ri][ci][1]) << 16);
        pk.y = (u32)f32_bf16(acc[ri][ci][2]) | ((u32)f32_bf16(acc[ri][ci][3]) << 16);
        *(uint2*)(s1 + (size_t)xr * 128 + wc * 64 + ci * 16 + kg * 4) = pk;
      }
    }
  }
}

// ---------------- fused in-LDS bucket sort preamble (shared by agg1/agg2) --
// Sorts the block's bucket segment of binned[] into se[] grouped by local
// dst (dl), building row offsets rs[dl]. Same work k_sort did, minus the
// 51 MB global round-trip.

#define SORT_PREAMBLE(binned)                                               \
  int t = threadIdx.x;                                                      \
  int b = blockIdx.x;                                                       \
  int beg = bb[b], end = bb[b + 1];                                         \
  int n = end - beg;                                                        \
  bool fits = (n <= STAGE_CAP);                                             \
  if (t < BKT_SIZE) cnt[t] = 0;                                             \
  __syncthreads();                                                          \
  if (fits) {                                                               \
    for (int i = t; i < n; i += 256)                                        \
      atomicAdd(&cnt[binned[beg + i].x >> 20], 1);                          \
    __syncthreads();                                                        \
    if (t < BKT_SIZE) sc[t] = cnt[t];                                       \
    __syncthreads();                                                        \
    for (int off = 1; off < BKT_SIZE; off <<= 1) {                          \
      int add = (t < BKT_SIZE && t >= off) ? sc[t - off] : 0;               \
      __syncthreads();                                                      \
      if (t < BKT_SIZE) sc[t] += add;                                       \
      __syncthreads();                                                      \
    }                                                                       \
    if (t < BKT_SIZE) { int ex = sc[t] - cnt[t]; rs[t] = ex; cur[t] = ex; } \
    if (t == 0) rs[BKT_SIZE] = n;                                           \
    __syncthreads();                                                        \
    for (int i = t; i < n; i += 256) {                                      \
      uint2 e = binned[beg + i];                                            \
      int pos = atomicAdd(&cur[e.x >> 20], 1);                              \
      se[pos] = e;                                                          \
    }                                                                       \
    __syncthreads();                                                        \
  }

// ---------------- layer-1 aggregate + bias + relu -> h[N][128] bf16 --------
// one block per bucket; in-LDS sort; then one wave per dst (32 dsts/wave
// sequential), 4 edges per wave-instruction, 16 in flight.

#define A1_EDGE(EV)                                            \
  {                                                            \
    u32 sI = (EV).x & 0xFFFFFu;                                \
    float wg = __uint_as_float((EV).y);                        \
    uint4 pw = s1u4[(size_t)sI * 16 + sub];                    \
    a0 += wg * bf_lo(pw.x); a1 += wg * bf_hi(pw.x);            \
    a2 += wg * bf_lo(pw.y); a3 += wg * bf_hi(pw.y);            \
    a4 += wg * bf_lo(pw.z); a5 += wg * bf_hi(pw.z);            \
    a6 += wg * bf_lo(pw.w); a7 += wg * bf_hi(pw.w);            \
  }

__global__ __launch_bounds__(256) void k_agg1(const uint2* __restrict__ binned,
                                              const int* __restrict__ bb,
                                              const uint4* __restrict__ s1u4,
                                              const float* __restrict__ b1,
                                              uint4* __restrict__ h_u4) {
  __shared__ uint2 se[STAGE_CAP + 4];
  __shared__ int cnt[BKT_SIZE];
  __shared__ int sc[BKT_SIZE];
  __shared__ int cur[BKT_SIZE];
  __shared__ int rs[BKT_SIZE + 1];
  SORT_PREAMBLE(binned)

  int wid = t >> 6, lane = t & 63;
  int q = lane >> 4, sub = lane & 15;
  int base_r = b * BKT_SIZE;
  for (int dl = wid * 32; dl < wid * 32 + 32; ++dl) {
    int dst = base_r + dl;
    if (dst >= N_NODES) break;
    float a0 = 0.f, a1 = 0.f, a2 = 0.f, a3 = 0.f;
    float a4 = 0.f, a5 = 0.f, a6 = 0.f, a7 = 0.f;
    if (fits) {
      int i = rs[dl], send = rs[dl + 1];
      for (; i + 16 <= send; i += 16) {
        uint2 eA = se[i + q];
        uint2 eB = se[i + 4 + q];
        uint2 eC = se[i + 8 + q];
        uint2 eD = se[i + 12 + q];
        A1_EDGE(eA);
        A1_EDGE(eB);
        A1_EDGE(eC);
        A1_EDGE(eD);
      }
      for (; i + 8 <= send; i += 8) {
        uint2 eA = se[i + q];
        uint2 eB = se[i + 4 + q];
        A1_EDGE(eA);
        A1_EDGE(eB);
      }
      for (; i < send; i += 4) {
        int idx = i + q;
        bool ok = idx < send;
        uint2 eA = ok ? se[idx] : make_uint2(0u, 0u);
        u32 sA = eA.x & 0xFFFFFu;
        float wA = ok ? __uint_as_float(eA.y) : 0.f;
        uint4 pA = s1u4[(size_t)sA * 16 + sub];
        a0 += wA * bf_lo(pA.x); a1 += wA * bf_hi(pA.x);
        a2 += wA * bf_lo(pA.y); a3 += wA * bf_hi(pA.y);
        a4 += wA * bf_lo(pA.z); a5 += wA * bf_hi(pA.z);
        a6 += wA * bf_lo(pA.w); a7 += wA * bf_hi(pA.w);
      }
    } else {
      // never-expected fallback: masked scan of whole bucket from global
      for (int i = beg; i < end; i += 4) {
        int idx = i + q;
        bool ok = idx < end;
        uint2 eA = ok ? binned[idx] : make_uint2(0u, 0u);
        bool mine = ok && (((eA.x >> 20) & 127u) == (u32)dl);
        u32 sA = eA.x & 0xFFFFFu;
        float wA = mine ? __uint_as_float(eA.y) : 0.f;
        uint4 pA = s1u4[(size_t)sA * 16 + sub];
        a0 += wA * bf_lo(pA.x); a1 += wA * bf_hi(pA.x);
        a2 += wA * bf_lo(pA.y); a3 += wA * bf_hi(pA.y);
        a4 += wA * bf_lo(pA.z); a5 += wA * bf_hi(pA.z);
        a6 += wA * bf_lo(pA.w); a7 += wA * bf_hi(pA.w);
      }
    }
    a0 += __shfl_xor(a0, 16); a1 += __shfl_xor(a1, 16);
    a2 += __shfl_xor(a2, 16); a3 += __shfl_xor(a3, 16);
    a4 += __shfl_xor(a4, 16); a5 += __shfl_xor(a5, 16);
    a6 += __shfl_xor(a6, 16); a7 += __shfl_xor(a7, 16);
    a0 += __shfl_xor(a0, 32); a1 += __shfl_xor(a1, 32);
    a2 += __shfl_xor(a2, 32); a3 += __shfl_xor(a3, 32);
    a4 += __shfl_xor(a4, 32); a5 += __shfl_xor(a5, 32);
    a6 += __shfl_xor(a6, 32); a7 += __shfl_xor(a7, 32);
    if (q == 0) {
      f32x4 bL = *(const f32x4*)(b1 + 8 * sub);
      f32x4 bH = *(const f32x4*)(b1 + 8 * sub + 4);
      float h0 = fmaxf(a0 + bL[0], 0.f), h1 = fmaxf(a1 + bL[1], 0.f);
      float h2 = fmaxf(a2 + bL[2], 0.f), h3 = fmaxf(a3 + bL[3], 0.f);
      float h4 = fmaxf(a4 + bH[0], 0.f), h5 = fmaxf(a5 + bH[1], 0.f);
      float h6 = fmaxf(a6 + bH[2], 0.f), h7 = fmaxf(a7 + bH[3], 0.f);
      uint4 pk;
      pk.x = (u32)f32_bf16(h0) | ((u32)f32_bf16(h1) << 16);
      pk.y = (u32)f32_bf16(h2) | ((u32)f32_bf16(h3) << 16);
      pk.z = (u32)f32_bf16(h4) | ((u32)f32_bf16(h5) << 16);
      pk.w = (u32)f32_bf16(h6) | ((u32)f32_bf16(h7) << 16);
      h_u4[(size_t)dst * 16 + sub] = pk;
    }
  }
}

// ---------------- GEMM2: support2[N][40] bf16 = h @ W2 (vector fp32) -------
// 32 rows per block (4x fewer W2->LDS reloads than 8 rows/block).

__global__ __launch_bounds__(320) void k_gemm2(const u16* __restrict__ h,
                                               const float* __restrict__ W2,
                                               u16* __restrict__ s2) {
  __shared__ float w2s[128 * 40];
  for (int i = threadIdx.x; i < 128 * 40; i += 320) w2s[i] = W2[i];
  __syncthreads();
  int g = threadIdx.x / 40;        // 0..7
  int c = threadIdx.x % 40;
  int r0 = blockIdx.x * 32 + g;    // rows r0 + 8j, j=0..3
  const u32* hu = (const u32*)h;
  float acc0 = 0.f, acc1 = 0.f, acc2 = 0.f, acc3 = 0.f;
#pragma unroll 8
  for (int k2 = 0; k2 < 64; ++k2) {
    float wlo = w2s[(2 * k2) * 40 + c];
    float whi = w2s[(2 * k2 + 1) * 40 + c];
    u32 p0 = hu[(size_t)(r0)      * 64 + k2];
    u32 p1 = hu[(size_t)(r0 + 8)  * 64 + k2];
    u32 p2 = hu[(size_t)(r0 + 16) * 64 + k2];
    u32 p3 = hu[(size_t)(r0 + 24) * 64 + k2];
    acc0 += bf_lo(p0) * wlo + bf_hi(p0) * whi;
    acc1 += bf_lo(p1) * wlo + bf_hi(p1) * whi;
    acc2 += bf_lo(p2) * wlo + bf_hi(p2) * whi;
    acc3 += bf_lo(p3) * wlo + bf_hi(p3) * whi;
  }
  s2[(size_t)(r0)      * 40 + c] = f32_bf16(acc0);
  s2[(size_t)(r0 + 8)  * 40 + c] = f32_bf16(acc1);
  s2[(size_t)(r0 + 16) * 40 + c] = f32_bf16(acc2);
  s2[(size_t)(r0 + 24) * 40 + c] = f32_bf16(acc3);
}

// ---------------- layer-2 aggregate + bias + log_softmax -> out ------------
// one block per bucket; in-LDS sort; one wave per dst, 3 edges per pass
// (20 lanes x u32), 12 in flight.

__global__ __launch_bounds__(256) void k_agg2(const uint2* __restrict__ binned,
                                              const int* __restrict__ bb,
                                              const u32* __restrict__ s2u,
                                              const float* __restrict__ b2,
                                              float* __restrict__ out) {
  __shared__ uint2 se[STAGE_CAP + 4];
  __shared__ int cnt[BKT_SIZE];
  __shared__ int sc[BKT_SIZE];
  __shared__ int cur[BKT_SIZE];
  __shared__ int rs[BKT_SIZE + 1];
  SORT_PREAMBLE(binned)

  int wid = t >> 6, lane = t & 63;
  u32 g = (u32)lane / 20u;
  u32 d = (u32)lane - 20u * g;
  bool act = lane < 20;
  for (int dl = wid * 32; dl < wid * 32 + 32; ++dl) {
    int dst = b * BKT_SIZE + dl;
    if (dst >= N_NODES) break;
    float a0 = 0.f, a1 = 0.f;
    if (fits) {
      int i = rs[dl], send = rs[dl + 1];
      for (; i + 12 <= send; i += 12) {
        uint2 e0 = se[i],     e1 = se[i + 1],  e2 = se[i + 2];
        uint2 e3 = se[i + 3], e4 = se[i + 4],  e5 = se[i + 5];
        uint2 e6 = se[i + 6], e7 = se[i + 7],  e8 = se[i + 8];
        uint2 e9 = se[i + 9], ea = se[i + 10], eb = se[i + 11];
        uint2 A = (g == 1) ? e1 : ((g == 2) ? e2 : e0);
        uint2 B = (g == 1) ? e4 : ((g == 2) ? e5 : e3);
        uint2 C = (g == 1) ? e7 : ((g == 2) ? e8 : e6);
        uint2 D = (g == 1) ? ea : ((g == 2) ? eb : e9);
        u32 sA = A.x & 0xFFFFFu, sB = B.x & 0xFFFFFu;
        u32 sC = C.x & 0xFFFFFu, sD = D.x & 0xFFFFFu;
        float wA = __uint_as_float(A.y), wB = __uint_as_float(B.y);
        float wC = __uint_as_float(C.y), wD = __uint_as_float(D.y);
        u32 pA = s2u[(size_t)sA * 20 + d];
        u32 pB = s2u[(size_t)sB * 20 + d];
        u32 pC = s2u[(size_t)sC * 20 + d];
        u32 pD = s2u[(size_t)sD * 20 + d];
        a0 += wA * bf_lo(pA); a1 += wA * bf_hi(pA);
        a0 += wB * bf_lo(pB); a1 += wB * bf_hi(pB);
        a0 += wC * bf_lo(pC); a1 += wC * bf_hi(pC);
        a0 += wD * bf_lo(pD); a1 += wD * bf_hi(pD);
      }
      for (; i + 6 <= send; i += 6) {
        uint2 e0 = se[i],     e1 = se[i + 1], e2 = se[i + 2];
        uint2 e3 = se[i + 3], e4 = se[i + 4], e5 = se[i + 5];
        uint2 A = (g == 1) ? e1 : ((g == 2) ? e2 : e0);
        uint2 B = (g == 1) ? e4 : ((g == 2) ? e5 : e3);
        u32 sA = A.x & 0xFFFFFu;
        u32 sB = B.x & 0xFFFFFu;
        float wA = __uint_as_float(A.y), wB = __uint_as_float(B.y);
        u32 pA = s2u[(size_t)sA * 20 + d];
        u32 pB = s2u[(size_t)sB * 20 + d];
        a0 += wA * bf_lo(pA); a1 += wA * bf_hi(pA);
        a0 += wB * bf_lo(pB); a1 += wB * bf_hi(pB);
      }
      for (; i < send; i += 3) {
        uint2 e0 = se[i];
        uint2 e1 = (i + 1 < send) ? se[i + 1] : make_uint2(e0.x, 0u);
        uint2 e2 = (i + 2 < send) ? se[i + 2] : make_uint2(e0.x, 0u);
        uint2 A = (g == 1) ? e1 : ((g == 2) ? e2 : e0);
        u32 sA = A.x & 0xFFFFFu;
        float wA = __uint_as_float(A.y);
        u32 pA = s2u[(size_t)sA * 20 + d];
        a0 += wA * bf_lo(pA); a1 += wA * bf_hi(pA);
      }
    } else {
      // never-expected fallback: masked scan of whole bucket from global
      for (int i = beg; i < end; i += 3) {
        uint2 e0 = binned[i];
        uint2 e1 = (i + 1 < end) ? binned[i + 1] : make_uint2(0u, 0u);
        uint2 e2 = (i + 2 < end) ? binned[i + 2] : make_uint2(0u, 0u);
        uint2 A = (g == 1) ? e1 : ((g == 2) ? e2 : e0);
        bool mine = (((A.x >> 20) & 127u) == (u32)dl);
        u32 sA = A.x & 0xFFFFFu;
        float wA = mine ? __uint_as_float(A.y) : 0.f;
        u32 pA = s2u[(size_t)sA * 20 + d];
        a0 += wA * bf_lo(pA); a1 += wA * bf_hi(pA);
      }
    }
    a0 += __shfl(a0, lane + 20) + __shfl(a0, lane + 40);
    a1 += __shfl(a1, lane + 20) + __shfl(a1, lane + 40);
    float v0 = -INFINITY, v1 = -INFINITY;
    if (act) {
      float2 bb2 = *(const float2*)(b2 + 2 * d);
      v0 = a0 + bb2.x;
      v1 = a1 + bb2.y;
    }
    float mx = fmaxf(v0, v1);
#pragma unroll
    for (int off = 16; off > 0; off >>= 1) mx = fmaxf(mx, __shfl_xor(mx, off));
    float esum = act ? (__expf(v0 - mx) + __expf(v1 - mx)) : 0.f;
#pragma unroll
    for (int off = 16; off > 0; off >>= 1) esum += __shfl_xor(esum, off);
    if (act) {
      float ls = __logf(esum);
      float2 o = make_float2((v0 - mx) - ls, (v1 - mx) - ls);
      *(float2*)(out + (size_t)dst * 40 + 2 * d) = o;
    }
  }
}

// ---------------- launch ----------------

extern "C" void kernel_launch(void* const* d_in, const int* in_sizes, int n_in,
                              void* d_out, int out_size, void* d_ws, size_t ws_size,
                              hipStream_t stream) {
  const float* x = (const float*)d_in[0];
  const int* ei = (const int*)d_in[1];     // int32 [2][E]
  const float* ew = (const float*)d_in[2];
  const float* W1 = (const float*)d_in[3];
  const float* b1 = (const float*)d_in[4];
  const float* W2 = (const float*)d_in[5];
  const float* b2 = (const float*)d_in[6];
  float* out = (float*)d_out;
  const int* eis = ei;             // src row
  const int* eid = ei + N_EDGES;   // dst row

  char* p = (char*)d_ws;
  u16* w1t = (u16*)p;           p += 128 * 512 * 2;                 // 128 KiB
  int* ghist = (int*)p;         p += 1024 * 4;
  int* bb = (int*)p;            p += 1024 * 4;
  int* gcur = (int*)p;          p += 1024 * 4;
  uint2* binned = (uint2*)p;    p += (size_t)N_EDGES * 8;           // 25.6 MB (live thru k_agg2)
  u16* h = (u16*)p;             p += (size_t)N_NODES * 128 * 2;     // 25.6 MB
  u16* s1 = (u16*)p;            p += (size_t)N_NODES * 128 * 2;     // 25.6 MB
  u16* s2 = s1;                 // s1 dead after k_agg1; alias

  const int nchunk = (N_EDGES + CHUNK - 1) / CHUNK;  // 782
  k_w1t<<<(512 * 128) / 256, 256, 0, stream>>>(W1, w1t);
  k_zero2<<<1, 1024, 0, stream>>>(ghist);
  k_hist<<<nchunk, 256, 0, stream>>>(eid, ghist);
  k_base<<<1, 1024, 0, stream>>>(ghist, bb, gcur);
  k_bin<<<nchunk, 256, 0, stream>>>(eis, eid, ew, gcur, binned);
  k_gemm1<<<(N_NODES + 127) / 128, 256, 0, stream>>>(x, w1t, s1);
  k_agg1<<<N_BKT, 256, 0, stream>>>(binned, bb, (const uint4*)s1, b1, (uint4*)h);
  k_gemm2<<<N_NODES / 32, 320, 0, stream>>>(h, W2, s2);
  k_agg2<<<N_BKT, 256, 0, stream>>>(binned, bb, (const u32*)s2, b2, out);
}

// Round 5
// 653.446 us; speedup vs baseline: 1.0538x; 1.0538x over previous
//
#include <hip/hip_runtime.h>
#include <stdint.h>

#define N_NODES 100000
#define N_EDGES 3200000
#define N_BKT 782          // ceil(100000/128)
#define BKT_SHIFT 7
#define BKT_SIZE 128
#define CHUNK 4096
#define STAGE_CAP 4608     // 8 sigma above mean bucket size 4096; 256*18

typedef unsigned int u32;
typedef unsigned short u16;
typedef short short8 __attribute__((ext_vector_type(8)));
typedef float f32x4 __attribute__((ext_vector_type(4)));

__device__ __forceinline__ u16 f32_bf16(float f) {
  u32 u = __float_as_uint(f);
  u += 0x7fffu + ((u >> 16) & 1u);   // RNE
  return (u16)(u >> 16);
}
__device__ __forceinline__ float bf_lo(u32 p) { return __uint_as_float(p << 16); }
__device__ __forceinline__ float bf_hi(u32 p) { return __uint_as_float(p & 0xffff0000u); }

#define GLOAD_LDS16(g, l)                                                  \
  __builtin_amdgcn_global_load_lds(                                        \
      (const __attribute__((address_space(1))) void*)(g),                  \
      (__attribute__((address_space(3))) void*)(l), 16, 0, 0)

// ---------------- bucket histogram ----------------

__global__ __launch_bounds__(1024) void k_zero2(int* ghist) {
  ghist[threadIdx.x] = 0;
}

__global__ __launch_bounds__(256) void k_hist(const int* __restrict__ eid,
                                              int* __restrict__ ghist) {
  __shared__ int hh[1024];
  int t = threadIdx.x;
  for (int b = t; b < 1024; b += 256) hh[b] = 0;
  __syncthreads();
  int base = blockIdx.x * CHUNK;
#pragma unroll
  for (int k = 0; k < 16; ++k) {
    int e = base + t + 256 * k;
    if (e < N_EDGES) atomicAdd(&hh[eid[e] >> BKT_SHIFT], 1);
  }
  __syncthreads();
  for (int b = t; b < 1024; b += 256) {
    int c = hh[b];
    if (c) atomicAdd(&ghist[b], c);
  }
}

// single-block scan of bucket counts -> bucket bases + cursors + sentinel
__global__ __launch_bounds__(1024) void k_base(const int* __restrict__ ghist,
                                               int* __restrict__ bb,
                                               int* __restrict__ gcur,
                                               int* __restrict__ row_start) {
  __shared__ int sm[1024];
  int t = threadIdx.x;
  int v = (t < N_BKT) ? ghist[t] : 0;
  sm[t] = v;
  __syncthreads();
  for (int off = 1; off < 1024; off <<= 1) {
    int add = (t >= off) ? sm[t - off] : 0;
    __syncthreads();
    sm[t] += add;
    __syncthreads();
  }
  int ex = sm[t] - v;
  if (t < N_BKT) { bb[t] = ex; gcur[t] = ex; }
  if (t == 0) { bb[N_BKT] = N_EDGES; row_start[N_NODES] = N_EDGES; }
}

// ---------------- binning: block-local counting sort + coalesced flush -----
// entry pack: x = src | (dst&127)<<20 ; y = weight fp32
// binned[] ends up grouped by bucket (order within bucket arbitrary).

__global__ __launch_bounds__(256) void k_bin(const int* __restrict__ eis,
                                             const int* __restrict__ eid,
                                             const float* __restrict__ ew,
                                             int* __restrict__ gcur,
                                             uint2* __restrict__ binned) {
  __shared__ int cnt[1024];
  __shared__ int lstart[1024];
  __shared__ int delta[1024];
  __shared__ int lcur[1024];
  __shared__ int part[256];
  __shared__ uint2 stage[CHUNK];
  __shared__ u16 sbkt[CHUNK];
  int t = threadIdx.x;
  for (int b = t; b < 1024; b += 256) cnt[b] = 0;
  __syncthreads();
  int base = blockIdx.x * CHUNK;
  int cc = N_EDGES - base; if (cc > CHUNK) cc = CHUNK;
#pragma unroll
  for (int k = 0; k < 16; ++k) {
    int e = base + t + 256 * k;
    if (e < N_EDGES) atomicAdd(&cnt[eid[e] >> BKT_SHIFT], 1);
  }
  __syncthreads();
  int b4 = t * 4;
  int c0 = cnt[b4], c1 = cnt[b4 + 1], c2 = cnt[b4 + 2], c3 = cnt[b4 + 3];
  int bs = c0 + c1 + c2 + c3;
  part[t] = bs;
  __syncthreads();
  for (int off = 1; off < 256; off <<= 1) {
    int add = (t >= off) ? part[t - off] : 0;
    __syncthreads();
    part[t] += add;
    __syncthreads();
  }
  int ex = part[t] - bs;
  lstart[b4] = ex;                    lcur[b4] = ex;
  lstart[b4 + 1] = ex + c0;           lcur[b4 + 1] = ex + c0;
  lstart[b4 + 2] = ex + c0 + c1;      lcur[b4 + 2] = ex + c0 + c1;
  lstart[b4 + 3] = ex + c0 + c1 + c2; lcur[b4 + 3] = ex + c0 + c1 + c2;
  __syncthreads();
  for (int b = t; b < 1024; b += 256) {
    int c = cnt[b];
    if (c) {
      int g = atomicAdd(&gcur[b], c);
      delta[b] = g - lstart[b];
    }
  }
#pragma unroll
  for (int k = 0; k < 16; ++k) {
    int e = base + t + 256 * k;
    if (e < N_EDGES) {
      int dst = eid[e];
      int bkt = dst >> BKT_SHIFT;
      int pos = atomicAdd(&lcur[bkt], 1);
      stage[pos] = make_uint2((u32)eis[e] | ((u32)(dst & (BKT_SIZE - 1)) << 20),
                              __float_as_uint(ew[e]));
      sbkt[pos] = (u16)bkt;
    }
  }
  __syncthreads();
  for (int idx = t; idx < cc; idx += 256) {
    int bkt = sbkt[idx];
    binned[delta[bkt] + idx] = stage[idx];
  }
}

// ---------------- W1 transpose+convert: W1t[c][k] bf16 ----------------

__global__ void k_w1t(const float* __restrict__ W1, u16* __restrict__ w1t) {
  int i = blockIdx.x * 256 + threadIdx.x;  // i = c*512 + k
  if (i < 512 * 128) {
    int c = i >> 9, k = i & 511;
    w1t[i] = f32_bf16(W1[k * 128 + c]);
  }
}

// ---------------- GEMM1: support1[N][128] bf16 = x @ W1 (MFMA 16x16x32) ----
// 128x128 block tile, K_STEP=32, 4 waves (2x2 quadrants), double-buffered LDS,
// global_load_lds staging with source-swizzled addresses.

#define G1_NSTEP 16  // 512 / 32

__global__ __launch_bounds__(256) void k_gemm1(const float* __restrict__ x,
                                               const u16* __restrict__ w1t,
                                               u16* __restrict__ s1) {
  __shared__ __align__(16) u16 aS[2][128 * 32];    // 8 KB per buffer
  __shared__ __align__(16) float bS[2][128 * 32];  // 16 KB per buffer

  int t = threadIdx.x;
  int w = t >> 6, lane = t & 63;
  int wr = w >> 1, wc = w & 1;           // 2x2 wave quadrants (64 rows x 64 cols)
  int rbase = blockIdx.x * 128;

  // A staging: c = p>>6, q = (p>>4)&3 ; stored slot q holds data slot q^((c>>1)&3)
  int pA0 = ((0 * 4 + w) << 10) + lane * 16;
  int pA1 = ((1 * 4 + w) << 10) + lane * 16;
  int cA0 = pA0 >> 6, qA0 = (pA0 >> 4) & 3;
  int cA1 = pA1 >> 6, qA1 = (pA1 >> 4) & 3;
  int sA0 = qA0 ^ ((cA0 >> 1) & 3);
  int sA1 = qA1 ^ ((cA1 >> 1) & 3);
  const u16* gA0 = w1t + (size_t)cA0 * 512 + sA0 * 8;
  const u16* gA1 = w1t + (size_t)cA1 * 512 + sA1 * 8;

  // B staging: r = p>>7, q = (p>>4)&7 ; slot = q ^ (r&7)
  const float* gB[4];
#pragma unroll
  for (int j = 0; j < 4; ++j) {
    int p = ((j * 4 + w) << 10) + lane * 16;
    int r = p >> 7, q = (p >> 4) & 7;
    int slot = q ^ (r & 7);
    int rg = rbase + r;
    if (rg > N_NODES - 1) rg = N_NODES - 1;
    gB[j] = x + (size_t)rg * 512 + slot * 4;
  }

  int c_lane = lane & 15;
  int slotA = lane >> 4;
  int slotB = (lane >> 4) * 2;

  int aOff[4], bOffLo[4], bOffHi[4];
#pragma unroll
  for (int ci = 0; ci < 4; ++ci) {
    int c = wc * 64 + ci * 16 + c_lane;
    aOff[ci] = c * 64 + ((slotA ^ ((c >> 1) & 3)) << 4);
  }
#pragma unroll
  for (int ri = 0; ri < 4; ++ri) {
    int r = wr * 64 + ri * 16 + c_lane;
    int m = r & 7;
    bOffLo[ri] = r * 128 + ((slotB ^ m) << 4);
    bOffHi[ri] = r * 128 + (((slotB + 1) ^ m) << 4);
  }

  f32x4 acc[4][4] = {};

  {
    char* la = (char*)&aS[0][0];
    char* lb = (char*)&bS[0][0];
    GLOAD_LDS16(gA0, la + pA0 - lane * 16);
    GLOAD_LDS16(gA1, la + pA1 - lane * 16);
#pragma unroll
    for (int j = 0; j < 4; ++j)
      GLOAD_LDS16(gB[j], lb + ((j * 4 + w) << 10));
  }
  __syncthreads();

  int buf = 0;
#pragma unroll 1
  for (int s = 0; s < G1_NSTEP; ++s) {
    if (s + 1 < G1_NSTEP) {
      int kk = (s + 1) * 32;
      char* la = (char*)&aS[buf ^ 1][0];
      char* lb = (char*)&bS[buf ^ 1][0];
      GLOAD_LDS16(gA0 + kk, la + pA0 - lane * 16);
      GLOAD_LDS16(gA1 + kk, la + pA1 - lane * 16);
#pragma unroll
      for (int j = 0; j < 4; ++j)
        GLOAD_LDS16(gB[j] + kk, lb + ((j * 4 + w) << 10));
    }

    const char* la = (const char*)&aS[buf][0];
    const char* lb = (const char*)&bS[buf][0];
    short8 af[4];
#pragma unroll
    for (int ci = 0; ci < 4; ++ci)
      af[ci] = *(const short8*)(la + aOff[ci]);
#pragma unroll
    for (int ri = 0; ri < 4; ++ri) {
      f32x4 lo = *(const f32x4*)(lb + bOffLo[ri]);
      f32x4 hi = *(const f32x4*)(lb + bOffHi[ri]);
      short8 bf;
      bf[0] = (short)f32_bf16(lo[0]);
      bf[1] = (short)f32_bf16(lo[1]);
      bf[2] = (short)f32_bf16(lo[2]);
      bf[3] = (short)f32_bf16(lo[3]);
      bf[4] = (short)f32_bf16(hi[0]);
      bf[5] = (short)f32_bf16(hi[1]);
      bf[6] = (short)f32_bf16(hi[2]);
      bf[7] = (short)f32_bf16(hi[3]);
#pragma unroll
      for (int ci = 0; ci < 4; ++ci)
        acc[ri][ci] = __builtin_amdgcn_mfma_f32_16x16x32_bf16(af[ci], bf, acc[ri][ci], 0, 0, 0);
    }
    __syncthreads();
    buf ^= 1;
  }

  int kg = lane >> 4;
#pragma unroll
  for (int ri = 0; ri < 4; ++ri) {
    int xr = rbase + wr * 64 + ri * 16 + c_lane;
    if (xr < N_NODES) {
#pragma unroll
      for (int ci = 0; ci < 4; ++ci) {
        uint2 pk;
        pk.x = (u32)f32_bf16(acc[ri][ci][0]) | ((u32)f32_bf16(acc[ri][ci][1]) << 16);
        pk.y = (u32)f32_bf16(acc[ri][ci][2]) | ((u32)f32_bf16(acc[ri][ci][3]) << 16);
        *(uint2*)(s1 + (size_t)xr * 128 + wc * 64 + ci * 16 + kg * 4) = pk;
      }
    }
  }
}

// ---------------- layer-1 aggregate + bias + relu -> h[N][128] bf16 --------
// one block per bucket. Register-staged in-LDS sort (ONE global pass over the
// bucket), writes sorted entries + row_start back for k_agg2, then aggregates
// from the LDS copy: one wave per dst, 4 edges/pass, 16 in flight.

#define A1_EDGE(EV)                                            \
  {                                                            \
    u32 sI = (EV).x & 0xFFFFFu;                                \
    float wg = __uint_as_float((EV).y);                        \
    uint4 pw = s1u4[(size_t)sI * 16 + sub];                    \
    a0 += wg * bf_lo(pw.x); a1 += wg * bf_hi(pw.x);            \
    a2 += wg * bf_lo(pw.y); a3 += wg * bf_hi(pw.y);            \
    a4 += wg * bf_lo(pw.z); a5 += wg * bf_hi(pw.z);            \
    a6 += wg * bf_lo(pw.w); a7 += wg * bf_hi(pw.w);            \
  }

__global__ __launch_bounds__(256) void k_agg1(const uint2* __restrict__ binned,
                                              const int* __restrict__ bb,
                                              const uint4* __restrict__ s1u4,
                                              const float* __restrict__ b1,
                                              uint4* __restrict__ h_u4,
                                              uint2* __restrict__ entries,
                                              int* __restrict__ row_start) {
  __shared__ uint2 se[STAGE_CAP];
  __shared__ int cnt[BKT_SIZE];
  __shared__ int sc[BKT_SIZE];
  __shared__ int cur[BKT_SIZE];
  __shared__ int rs[BKT_SIZE + 1];
  int t = threadIdx.x;
  int b = blockIdx.x;
  int beg = bb[b], end = bb[b + 1];
  int n = end - beg;
  bool fits = (n <= STAGE_CAP);
  if (t < BKT_SIZE) cnt[t] = 0;
  __syncthreads();
  if (fits) {
    // ---- single global pass: stage bucket edges into registers ----
    uint2 er[18];
#pragma unroll
    for (int k = 0; k < 18; ++k) {
      int idx = t + 256 * k;
      int cidx = idx < n ? idx : (n - 1);
      er[k] = binned[beg + cidx];
    }
#pragma unroll
    for (int k = 0; k < 18; ++k) {
      if (t + 256 * k < n) atomicAdd(&cnt[(er[k].x >> 20) & 127u], 1);
    }
    __syncthreads();
    if (t < BKT_SIZE) sc[t] = cnt[t];
    __syncthreads();
    for (int off = 1; off < BKT_SIZE; off <<= 1) {
      int add = (t < BKT_SIZE && t >= off) ? sc[t - off] : 0;
      __syncthreads();
      if (t < BKT_SIZE) sc[t] += add;
      __syncthreads();
    }
    if (t < BKT_SIZE) {
      int ex = sc[t] - cnt[t];
      rs[t] = ex; cur[t] = ex;
      int dstg = b * BKT_SIZE + t;
      if (dstg < N_NODES) row_start[dstg] = beg + ex;
    }
    if (t == 0) rs[BKT_SIZE] = n;
    __syncthreads();
#pragma unroll
    for (int k = 0; k < 18; ++k) {
      if (t + 256 * k < n) {
        int pos = atomicAdd(&cur[(er[k].x >> 20) & 127u], 1);
        se[pos] = er[k];
      }
    }
    __syncthreads();
    // coalesced writeback of sorted edges for k_agg2
    for (int i = t; i < n; i += 256) entries[beg + i] = se[i];
  } else {
    // never-expected fallback: unsorted copy + degenerate row_start
    if (t < BKT_SIZE) {
      int dstg = b * BKT_SIZE + t;
      if (dstg < N_NODES) row_start[dstg] = beg;
    }
    for (int i = t; i < n; i += 256) entries[beg + i] = binned[beg + i];
    __syncthreads();
  }

  int wid = t >> 6, lane = t & 63;
  int q = lane >> 4, sub = lane & 15;
  int base_r = b * BKT_SIZE;
  for (int dl = wid * 32; dl < wid * 32 + 32; ++dl) {
    int dst = base_r + dl;
    if (dst >= N_NODES) break;
    float a0 = 0.f, a1 = 0.f, a2 = 0.f, a3 = 0.f;
    float a4 = 0.f, a5 = 0.f, a6 = 0.f, a7 = 0.f;
    if (fits) {
      int i = rs[dl], send = rs[dl + 1];
      for (; i + 16 <= send; i += 16) {
        uint2 eA = se[i + q];
        uint2 eB = se[i + 4 + q];
        uint2 eC = se[i + 8 + q];
        uint2 eD = se[i + 12 + q];
        A1_EDGE(eA);
        A1_EDGE(eB);
        A1_EDGE(eC);
        A1_EDGE(eD);
      }
      for (; i + 8 <= send; i += 8) {
        uint2 eA = se[i + q];
        uint2 eB = se[i + 4 + q];
        A1_EDGE(eA);
        A1_EDGE(eB);
      }
      for (; i < send; i += 4) {
        int idx = i + q;
        bool ok = idx < send;
        uint2 eA = ok ? se[idx] : make_uint2(0u, 0u);
        u32 sA = eA.x & 0xFFFFFu;
        float wA = ok ? __uint_as_float(eA.y) : 0.f;
        uint4 pA = s1u4[(size_t)sA * 16 + sub];
        a0 += wA * bf_lo(pA.x); a1 += wA * bf_hi(pA.x);
        a2 += wA * bf_lo(pA.y); a3 += wA * bf_hi(pA.y);
        a4 += wA * bf_lo(pA.z); a5 += wA * bf_hi(pA.z);
        a6 += wA * bf_lo(pA.w); a7 += wA * bf_hi(pA.w);
      }
    } else {
      // never-expected fallback: masked scan of whole bucket from global
      for (int i = beg; i < end; i += 4) {
        int idx = i + q;
        bool ok = idx < end;
        uint2 eA = ok ? binned[idx] : make_uint2(0u, 0u);
        bool mine = ok && (((eA.x >> 20) & 127u) == (u32)dl);
        u32 sA = eA.x & 0xFFFFFu;
        float wA = mine ? __uint_as_float(eA.y) : 0.f;
        uint4 pA = s1u4[(size_t)sA * 16 + sub];
        a0 += wA * bf_lo(pA.x); a1 += wA * bf_hi(pA.x);
        a2 += wA * bf_lo(pA.y); a3 += wA * bf_hi(pA.y);
        a4 += wA * bf_lo(pA.z); a5 += wA * bf_hi(pA.z);
        a6 += wA * bf_lo(pA.w); a7 += wA * bf_hi(pA.w);
      }
    }
    a0 += __shfl_xor(a0, 16); a1 += __shfl_xor(a1, 16);
    a2 += __shfl_xor(a2, 16); a3 += __shfl_xor(a3, 16);
    a4 += __shfl_xor(a4, 16); a5 += __shfl_xor(a5, 16);
    a6 += __shfl_xor(a6, 16); a7 += __shfl_xor(a7, 16);
    a0 += __shfl_xor(a0, 32); a1 += __shfl_xor(a1, 32);
    a2 += __shfl_xor(a2, 32); a3 += __shfl_xor(a3, 32);
    a4 += __shfl_xor(a4, 32); a5 += __shfl_xor(a5, 32);
    a6 += __shfl_xor(a6, 32); a7 += __shfl_xor(a7, 32);
    if (q == 0) {
      f32x4 bL = *(const f32x4*)(b1 + 8 * sub);
      f32x4 bH = *(const f32x4*)(b1 + 8 * sub + 4);
      float h0 = fmaxf(a0 + bL[0], 0.f), h1 = fmaxf(a1 + bL[1], 0.f);
      float h2 = fmaxf(a2 + bL[2], 0.f), h3 = fmaxf(a3 + bL[3], 0.f);
      float h4 = fmaxf(a4 + bH[0], 0.f), h5 = fmaxf(a5 + bH[1], 0.f);
      float h6 = fmaxf(a6 + bH[2], 0.f), h7 = fmaxf(a7 + bH[3], 0.f);
      uint4 pk;
      pk.x = (u32)f32_bf16(h0) | ((u32)f32_bf16(h1) << 16);
      pk.y = (u32)f32_bf16(h2) | ((u32)f32_bf16(h3) << 16);
      pk.z = (u32)f32_bf16(h4) | ((u32)f32_bf16(h5) << 16);
      pk.w = (u32)f32_bf16(h6) | ((u32)f32_bf16(h7) << 16);
      h_u4[(size_t)dst * 16 + sub] = pk;
    }
  }
}

// ---------------- GEMM2: support2[N][40] bf16 = h @ W2 (vector fp32) -------
// 32 rows per block (4x fewer W2->LDS reloads than 8 rows/block).

__global__ __launch_bounds__(320) void k_gemm2(const u16* __restrict__ h,
                                               const float* __restrict__ W2,
                                               u16* __restrict__ s2) {
  __shared__ float w2s[128 * 40];
  for (int i = threadIdx.x; i < 128 * 40; i += 320) w2s[i] = W2[i];
  __syncthreads();
  int g = threadIdx.x / 40;        // 0..7
  int c = threadIdx.x % 40;
  int r0 = blockIdx.x * 32 + g;    // rows r0 + 8j, j=0..3
  const u32* hu = (const u32*)h;
  float acc0 = 0.f, acc1 = 0.f, acc2 = 0.f, acc3 = 0.f;
#pragma unroll 8
  for (int k2 = 0; k2 < 64; ++k2) {
    float wlo = w2s[(2 * k2) * 40 + c];
    float whi = w2s[(2 * k2 + 1) * 40 + c];
    u32 p0 = hu[(size_t)(r0)      * 64 + k2];
    u32 p1 = hu[(size_t)(r0 + 8)  * 64 + k2];
    u32 p2 = hu[(size_t)(r0 + 16) * 64 + k2];
    u32 p3 = hu[(size_t)(r0 + 24) * 64 + k2];
    acc0 += bf_lo(p0) * wlo + bf_hi(p0) * whi;
    acc1 += bf_lo(p1) * wlo + bf_hi(p1) * whi;
    acc2 += bf_lo(p2) * wlo + bf_hi(p2) * whi;
    acc3 += bf_lo(p3) * wlo + bf_hi(p3) * whi;
  }
  s2[(size_t)(r0)      * 40 + c] = f32_bf16(acc0);
  s2[(size_t)(r0 + 8)  * 40 + c] = f32_bf16(acc1);
  s2[(size_t)(r0 + 16) * 40 + c] = f32_bf16(acc2);
  s2[(size_t)(r0 + 24) * 40 + c] = f32_bf16(acc3);
}

// ---------------- layer-2 aggregate + bias + log_softmax -> out ------------
// one wave per dst from the CSR k_agg1 produced; 3 edges/pass, 12 in flight.

__global__ __launch_bounds__(256) void k_agg2(const uint2* __restrict__ entries,
                                              const int* __restrict__ row_start,
                                              const int* __restrict__ bb,
                                              const u32* __restrict__ s2u,
                                              const float* __restrict__ b2,
                                              float* __restrict__ out) {
  int wid = threadIdx.x >> 6, lane = threadIdx.x & 63;
  int dst = __builtin_amdgcn_readfirstlane(blockIdx.x * 4 + wid);
  if (dst >= N_NODES) return;
  int bkt = dst >> BKT_SHIFT;
  int bbeg = bb[bkt], bend = bb[bkt + 1];
  bool fits = (bend - bbeg) <= STAGE_CAP;
  u32 g = (u32)lane / 20u;
  u32 d = (u32)lane - 20u * g;
  float a0 = 0.f, a1 = 0.f;
  if (fits) {
    int beg = row_start[dst], end = row_start[dst + 1];
    int i = beg;
    for (; i + 12 <= end; i += 12) {
      uint2 e0 = entries[i],     e1 = entries[i + 1],  e2 = entries[i + 2];
      uint2 e3 = entries[i + 3], e4 = entries[i + 4],  e5 = entries[i + 5];
      uint2 e6 = entries[i + 6], e7 = entries[i + 7],  e8 = entries[i + 8];
      uint2 e9 = entries[i + 9], ea = entries[i + 10], eb = entries[i + 11];
      uint2 A = (g == 1) ? e1 : ((g == 2) ? e2 : e0);
      uint2 B = (g == 1) ? e4 : ((g == 2) ? e5 : e3);
      uint2 C = (g == 1) ? e7 : ((g == 2) ? e8 : e6);
      uint2 D = (g == 1) ? ea : ((g == 2) ? eb : e9);
      u32 sA = A.x & 0xFFFFFu, sB = B.x & 0xFFFFFu;
      u32 sC = C.x & 0xFFFFFu, sD = D.x & 0xFFFFFu;
      float wA = __uint_as_float(A.y), wB = __uint_as_float(B.y);
      float wC = __uint_as_float(C.y), wD = __uint_as_float(D.y);
      u32 pA = s2u[(size_t)sA * 20 + d];
      u32 pB = s2u[(size_t)sB * 20 + d];
      u32 pC = s2u[(size_t)sC * 20 + d];
      u32 pD = s2u[(size_t)sD * 20 + d];
      a0 += wA * bf_lo(pA); a1 += wA * bf_hi(pA);
      a0 += wB * bf_lo(pB); a1 += wB * bf_hi(pB);
      a0 += wC * bf_lo(pC); a1 += wC * bf_hi(pC);
      a0 += wD * bf_lo(pD); a1 += wD * bf_hi(pD);
    }
    for (; i + 6 <= end; i += 6) {
      uint2 e0 = entries[i],     e1 = entries[i + 1], e2 = entries[i + 2];
      uint2 e3 = entries[i + 3], e4 = entries[i + 4], e5 = entries[i + 5];
      uint2 A = (g == 1) ? e1 : ((g == 2) ? e2 : e0);
      uint2 B = (g == 1) ? e4 : ((g == 2) ? e5 : e3);
      u32 sA = A.x & 0xFFFFFu;
      u32 sB = B.x & 0xFFFFFu;
      float wA = __uint_as_float(A.y), wB = __uint_as_float(B.y);
      u32 pA = s2u[(size_t)sA * 20 + d];
      u32 pB = s2u[(size_t)sB * 20 + d];
      a0 += wA * bf_lo(pA); a1 += wA * bf_hi(pA);
      a0 += wB * bf_lo(pB); a1 += wB * bf_hi(pB);
    }
    for (; i < end; i += 3) {
      uint2 e0 = entries[i];
      uint2 e1 = (i + 1 < end) ? entries[i + 1] : make_uint2(e0.x, 0u);
      uint2 e2 = (i + 2 < end) ? entries[i + 2] : make_uint2(e0.x, 0u);
      uint2 A = (g == 1) ? e1 : ((g == 2) ? e2 : e0);
      u32 sA = A.x & 0xFFFFFu;
      float wA = __uint_as_float(A.y);
      u32 pA = s2u[(size_t)sA * 20 + d];
      a0 += wA * bf_lo(pA); a1 += wA * bf_hi(pA);
    }
  } else {
    // never-expected fallback: masked scan of whole (unsorted) bucket
    u32 dl = (u32)(dst & (BKT_SIZE - 1));
    for (int i = bbeg; i < bend; i += 3) {
      uint2 e0 = entries[i];
      uint2 e1 = (i + 1 < bend) ? entries[i + 1] : make_uint2(0u, 0u);
      uint2 e2 = (i + 2 < bend) ? entries[i + 2] : make_uint2(0u, 0u);
      uint2 A = (g == 1) ? e1 : ((g == 2) ? e2 : e0);
      bool mine = (((A.x >> 20) & 127u) == dl);
      u32 sA = A.x & 0xFFFFFu;
      float wA = mine ? __uint_as_float(A.y) : 0.f;
      u32 pA = s2u[(size_t)sA * 20 + d];
      a0 += wA * bf_lo(pA); a1 += wA * bf_hi(pA);
    }
  }
  a0 += __shfl(a0, lane + 20) + __shfl(a0, lane + 40);
  a1 += __shfl(a1, lane + 20) + __shfl(a1, lane + 40);
  bool act = lane < 20;
  float v0 = -INFINITY, v1 = -INFINITY;
  if (act) {
    float2 bb2 = *(const float2*)(b2 + 2 * d);
    v0 = a0 + bb2.x;
    v1 = a1 + bb2.y;
  }
  float mx = fmaxf(v0, v1);
#pragma unroll
  for (int off = 16; off > 0; off >>= 1) mx = fmaxf(mx, __shfl_xor(mx, off));
  float e = act ? (__expf(v0 - mx) + __expf(v1 - mx)) : 0.f;
#pragma unroll
  for (int off = 16; off > 0; off >>= 1) e += __shfl_xor(e, off);
  if (act) {
    float ls = __logf(e);
    float2 o = make_float2((v0 - mx) - ls, (v1 - mx) - ls);
    *(float2*)(out + (size_t)dst * 40 + 2 * d) = o;
  }
}

// ---------------- launch ----------------

extern "C" void kernel_launch(void* const* d_in, const int* in_sizes, int n_in,
                              void* d_out, int out_size, void* d_ws, size_t ws_size,
                              hipStream_t stream) {
  const float* x = (const float*)d_in[0];
  const int* ei = (const int*)d_in[1];     // int32 [2][E]
  const float* ew = (const float*)d_in[2];
  const float* W1 = (const float*)d_in[3];
  const float* b1 = (const float*)d_in[4];
  const float* W2 = (const float*)d_in[5];
  const float* b2 = (const float*)d_in[6];
  float* out = (float*)d_out;
  const int* eis = ei;             // src row
  const int* eid = ei + N_EDGES;   // dst row

  char* p = (char*)d_ws;
  u16* w1t = (u16*)p;           p += 128 * 512 * 2;                 // 128 KiB
  int* ghist = (int*)p;         p += 1024 * 4;
  int* bb = (int*)p;            p += 1024 * 4;
  int* gcur = (int*)p;          p += 1024 * 4;
  int* row_start = (int*)p;     p += 100352 * 4;
  uint2* binned = (uint2*)p;    p += (size_t)N_EDGES * 8;           // 25.6 MB (live thru k_agg1)
  uint2* entries = (uint2*)p;   p += (size_t)N_EDGES * 8;           // 25.6 MB (written by k_agg1)
  u16* h = (u16*)p;             p += (size_t)N_NODES * 128 * 2;     // 25.6 MB
  u16* s1 = (u16*)p;            p += (size_t)N_NODES * 128 * 2;     // 25.6 MB
  u16* s2 = s1;                 // s1 dead after k_agg1; alias

  const int nchunk = (N_EDGES + CHUNK - 1) / CHUNK;  // 782
  k_w1t<<<(512 * 128) / 256, 256, 0, stream>>>(W1, w1t);
  k_zero2<<<1, 1024, 0, stream>>>(ghist);
  k_hist<<<nchunk, 256, 0, stream>>>(eid, ghist);
  k_base<<<1, 1024, 0, stream>>>(ghist, bb, gcur, row_start);
  k_bin<<<nchunk, 256, 0, stream>>>(eis, eid, ew, gcur, binned);
  k_gemm1<<<(N_NODES + 127) / 128, 256, 0, stream>>>(x, w1t, s1);
  k_agg1<<<N_BKT, 256, 0, stream>>>(binned, bb, (const uint4*)s1, b1, (uint4*)h,
                                    entries, row_start);
  k_gemm2<<<N_NODES / 32, 320, 0, stream>>>(h, W2, s2);
  k_agg2<<<N_NODES / 4, 256, 0, stream>>>(entries, row_start, bb, (const u32*)s2, b2, out);
}

// Round 6
// 648.443 us; speedup vs baseline: 1.0620x; 1.0077x over previous
//
#include <hip/hip_runtime.h>
#include <stdint.h>

#define N_NODES 100000
#define N_EDGES 3200000
#define N_BKT 782          // ceil(100000/128)
#define BKT_SHIFT 7
#define BKT_SIZE 128
#define CHUNK 4096
#define STAGE_CAP 4608     // 8 sigma above mean bucket size 4096; 256*18

typedef unsigned int u32;
typedef unsigned short u16;
typedef short short8 __attribute__((ext_vector_type(8)));
typedef float f32x4 __attribute__((ext_vector_type(4)));

__device__ __forceinline__ u16 f32_bf16(float f) {
  u32 u = __float_as_uint(f);
  u += 0x7fffu + ((u >> 16) & 1u);   // RNE
  return (u16)(u >> 16);
}
// HW packed convert: dst = {bf16(lo), bf16(hi)} in one VALU instruction.
__device__ __forceinline__ u32 cvt_pk_bf16(float lo, float hi) {
  u32 r;
  asm("v_cvt_pk_bf16_f32 %0, %1, %2" : "=v"(r) : "v"(lo), "v"(hi));
  return r;
}
__device__ __forceinline__ float bf_lo(u32 p) { return __uint_as_float(p << 16); }
__device__ __forceinline__ float bf_hi(u32 p) { return __uint_as_float(p & 0xffff0000u); }

#define GLOAD_LDS16(g, l)                                                  \
  __builtin_amdgcn_global_load_lds(                                        \
      (const __attribute__((address_space(1))) void*)(g),                  \
      (__attribute__((address_space(3))) void*)(l), 16, 0, 0)

// ---------------- bucket histogram ----------------

__global__ __launch_bounds__(1024) void k_zero2(int* ghist) {
  ghist[threadIdx.x] = 0;
}

__global__ __launch_bounds__(256) void k_hist(const int* __restrict__ eid,
                                              int* __restrict__ ghist) {
  __shared__ int hh[1024];
  int t = threadIdx.x;
  for (int b = t; b < 1024; b += 256) hh[b] = 0;
  __syncthreads();
  int base = blockIdx.x * CHUNK;
#pragma unroll
  for (int k = 0; k < 16; ++k) {
    int e = base + t + 256 * k;
    if (e < N_EDGES) atomicAdd(&hh[eid[e] >> BKT_SHIFT], 1);
  }
  __syncthreads();
  for (int b = t; b < 1024; b += 256) {
    int c = hh[b];
    if (c) atomicAdd(&ghist[b], c);
  }
}

// single-block scan of bucket counts -> bucket bases + cursors + sentinel
__global__ __launch_bounds__(1024) void k_base(const int* __restrict__ ghist,
                                               int* __restrict__ bb,
                                               int* __restrict__ gcur,
                                               int* __restrict__ row_start) {
  __shared__ int sm[1024];
  int t = threadIdx.x;
  int v = (t < N_BKT) ? ghist[t] : 0;
  sm[t] = v;
  __syncthreads();
  for (int off = 1; off < 1024; off <<= 1) {
    int add = (t >= off) ? sm[t - off] : 0;
    __syncthreads();
    sm[t] += add;
    __syncthreads();
  }
  int ex = sm[t] - v;
  if (t < N_BKT) { bb[t] = ex; gcur[t] = ex; }
  if (t == 0) { bb[N_BKT] = N_EDGES; row_start[N_NODES] = N_EDGES; }
}

// ---------------- binning: block-local counting sort + coalesced flush -----
// entry pack: x = src | (dst&127)<<20 ; y = weight fp32
// binned[] ends up grouped by bucket (order within bucket arbitrary).

__global__ __launch_bounds__(256) void k_bin(const int* __restrict__ eis,
                                             const int* __restrict__ eid,
                                             const float* __restrict__ ew,
                                             int* __restrict__ gcur,
                                             uint2* __restrict__ binned) {
  __shared__ int cnt[1024];
  __shared__ int lstart[1024];
  __shared__ int delta[1024];
  __shared__ int lcur[1024];
  __shared__ int part[256];
  __shared__ uint2 stage[CHUNK];
  __shared__ u16 sbkt[CHUNK];
  int t = threadIdx.x;
  for (int b = t; b < 1024; b += 256) cnt[b] = 0;
  __syncthreads();
  int base = blockIdx.x * CHUNK;
  int cc = N_EDGES - base; if (cc > CHUNK) cc = CHUNK;
#pragma unroll
  for (int k = 0; k < 16; ++k) {
    int e = base + t + 256 * k;
    if (e < N_EDGES) atomicAdd(&cnt[eid[e] >> BKT_SHIFT], 1);
  }
  __syncthreads();
  int b4 = t * 4;
  int c0 = cnt[b4], c1 = cnt[b4 + 1], c2 = cnt[b4 + 2], c3 = cnt[b4 + 3];
  int bs = c0 + c1 + c2 + c3;
  part[t] = bs;
  __syncthreads();
  for (int off = 1; off < 256; off <<= 1) {
    int add = (t >= off) ? part[t - off] : 0;
    __syncthreads();
    part[t] += add;
    __syncthreads();
  }
  int ex = part[t] - bs;
  lstart[b4] = ex;                    lcur[b4] = ex;
  lstart[b4 + 1] = ex + c0;           lcur[b4 + 1] = ex + c0;
  lstart[b4 + 2] = ex + c0 + c1;      lcur[b4 + 2] = ex + c0 + c1;
  lstart[b4 + 3] = ex + c0 + c1 + c2; lcur[b4 + 3] = ex + c0 + c1 + c2;
  __syncthreads();
  for (int b = t; b < 1024; b += 256) {
    int c = cnt[b];
    if (c) {
      int g = atomicAdd(&gcur[b], c);
      delta[b] = g - lstart[b];
    }
  }
#pragma unroll
  for (int k = 0; k < 16; ++k) {
    int e = base + t + 256 * k;
    if (e < N_EDGES) {
      int dst = eid[e];
      int bkt = dst >> BKT_SHIFT;
      int pos = atomicAdd(&lcur[bkt], 1);
      stage[pos] = make_uint2((u32)eis[e] | ((u32)(dst & (BKT_SIZE - 1)) << 20),
                              __float_as_uint(ew[e]));
      sbkt[pos] = (u16)bkt;
    }
  }
  __syncthreads();
  for (int idx = t; idx < cc; idx += 256) {
    int bkt = sbkt[idx];
    binned[delta[bkt] + idx] = stage[idx];
  }
}

// ---------------- W1 transpose+convert: W1t[c][k] bf16 ----------------

__global__ void k_w1t(const float* __restrict__ W1, u16* __restrict__ w1t) {
  int i = blockIdx.x * 256 + threadIdx.x;  // i = c*512 + k
  if (i < 512 * 128) {
    int c = i >> 9, k = i & 511;
    w1t[i] = f32_bf16(W1[k * 128 + c]);
  }
}

// ---------------- GEMM1: support1[N][128] bf16 = x @ W1 (MFMA 16x16x32) ----
// 128x128 block tile, K_STEP=32, 4 waves (2x2 quadrants), double-buffered LDS,
// global_load_lds staging with source-swizzled addresses. B-fragment fp32->
// bf16 via v_cvt_pk_bf16_f32 (4 instr instead of ~40 manual bit-ops).

#define G1_NSTEP 16  // 512 / 32

__global__ __launch_bounds__(256) void k_gemm1(const float* __restrict__ x,
                                               const u16* __restrict__ w1t,
                                               u16* __restrict__ s1) {
  __shared__ __align__(16) u16 aS[2][128 * 32];    // 8 KB per buffer
  __shared__ __align__(16) float bS[2][128 * 32];  // 16 KB per buffer

  int t = threadIdx.x;
  int w = t >> 6, lane = t & 63;
  int wr = w >> 1, wc = w & 1;           // 2x2 wave quadrants (64 rows x 64 cols)
  int rbase = blockIdx.x * 128;

  // A staging: c = p>>6, q = (p>>4)&3 ; stored slot q holds data slot q^((c>>1)&3)
  int pA0 = ((0 * 4 + w) << 10) + lane * 16;
  int pA1 = ((1 * 4 + w) << 10) + lane * 16;
  int cA0 = pA0 >> 6, qA0 = (pA0 >> 4) & 3;
  int cA1 = pA1 >> 6, qA1 = (pA1 >> 4) & 3;
  int sA0 = qA0 ^ ((cA0 >> 1) & 3);
  int sA1 = qA1 ^ ((cA1 >> 1) & 3);
  const u16* gA0 = w1t + (size_t)cA0 * 512 + sA0 * 8;
  const u16* gA1 = w1t + (size_t)cA1 * 512 + sA1 * 8;

  // B staging: r = p>>7, q = (p>>4)&7 ; slot = q ^ (r&7)
  const float* gB[4];
#pragma unroll
  for (int j = 0; j < 4; ++j) {
    int p = ((j * 4 + w) << 10) + lane * 16;
    int r = p >> 7, q = (p >> 4) & 7;
    int slot = q ^ (r & 7);
    int rg = rbase + r;
    if (rg > N_NODES - 1) rg = N_NODES - 1;
    gB[j] = x + (size_t)rg * 512 + slot * 4;
  }

  int c_lane = lane & 15;
  int slotA = lane >> 4;
  int slotB = (lane >> 4) * 2;

  int aOff[4], bOffLo[4], bOffHi[4];
#pragma unroll
  for (int ci = 0; ci < 4; ++ci) {
    int c = wc * 64 + ci * 16 + c_lane;
    aOff[ci] = c * 64 + ((slotA ^ ((c >> 1) & 3)) << 4);
  }
#pragma unroll
  for (int ri = 0; ri < 4; ++ri) {
    int r = wr * 64 + ri * 16 + c_lane;
    int m = r & 7;
    bOffLo[ri] = r * 128 + ((slotB ^ m) << 4);
    bOffHi[ri] = r * 128 + (((slotB + 1) ^ m) << 4);
  }

  f32x4 acc[4][4] = {};

  {
    char* la = (char*)&aS[0][0];
    char* lb = (char*)&bS[0][0];
    GLOAD_LDS16(gA0, la + pA0 - lane * 16);
    GLOAD_LDS16(gA1, la + pA1 - lane * 16);
#pragma unroll
    for (int j = 0; j < 4; ++j)
      GLOAD_LDS16(gB[j], lb + ((j * 4 + w) << 10));
  }
  __syncthreads();

  int buf = 0;
#pragma unroll 1
  for (int s = 0; s < G1_NSTEP; ++s) {
    if (s + 1 < G1_NSTEP) {
      int kk = (s + 1) * 32;
      char* la = (char*)&aS[buf ^ 1][0];
      char* lb = (char*)&bS[buf ^ 1][0];
      GLOAD_LDS16(gA0 + kk, la + pA0 - lane * 16);
      GLOAD_LDS16(gA1 + kk, la + pA1 - lane * 16);
#pragma unroll
      for (int j = 0; j < 4; ++j)
        GLOAD_LDS16(gB[j] + kk, lb + ((j * 4 + w) << 10));
    }

    const char* la = (const char*)&aS[buf][0];
    const char* lb = (const char*)&bS[buf][0];
    short8 af[4];
#pragma unroll
    for (int ci = 0; ci < 4; ++ci)
      af[ci] = *(const short8*)(la + aOff[ci]);
#pragma unroll
    for (int ri = 0; ri < 4; ++ri) {
      f32x4 lo = *(const f32x4*)(lb + bOffLo[ri]);
      f32x4 hi = *(const f32x4*)(lb + bOffHi[ri]);
      uint4 bu;
      bu.x = cvt_pk_bf16(lo[0], lo[1]);
      bu.y = cvt_pk_bf16(lo[2], lo[3]);
      bu.z = cvt_pk_bf16(hi[0], hi[1]);
      bu.w = cvt_pk_bf16(hi[2], hi[3]);
      short8 bf = __builtin_bit_cast(short8, bu);
#pragma unroll
      for (int ci = 0; ci < 4; ++ci)
        acc[ri][ci] = __builtin_amdgcn_mfma_f32_16x16x32_bf16(af[ci], bf, acc[ri][ci], 0, 0, 0);
    }
    __syncthreads();
    buf ^= 1;
  }

  int kg = lane >> 4;
#pragma unroll
  for (int ri = 0; ri < 4; ++ri) {
    int xr = rbase + wr * 64 + ri * 16 + c_lane;
    if (xr < N_NODES) {
#pragma unroll
      for (int ci = 0; ci < 4; ++ci) {
        uint2 pk;
        pk.x = cvt_pk_bf16(acc[ri][ci][0], acc[ri][ci][1]);
        pk.y = cvt_pk_bf16(acc[ri][ci][2], acc[ri][ci][3]);
        *(uint2*)(s1 + (size_t)xr * 128 + wc * 64 + ci * 16 + kg * 4) = pk;
      }
    }
  }
}

// ---------------- layer-1 aggregate + bias + relu -> h[N][128] bf16 --------
// one block per bucket. Register-staged in-LDS sort (ONE global pass over the
// bucket), writes sorted entries + row_start back for k_agg2, then aggregates
// from the LDS copy: one wave per dst, 4 edges/pass, 16 in flight.

#define A1_EDGE(EV)                                            \
  {                                                            \
    u32 sI = (EV).x & 0xFFFFFu;                                \
    float wg = __uint_as_float((EV).y);                        \
    uint4 pw = s1u4[(size_t)sI * 16 + sub];                    \
    a0 += wg * bf_lo(pw.x); a1 += wg * bf_hi(pw.x);            \
    a2 += wg * bf_lo(pw.y); a3 += wg * bf_hi(pw.y);            \
    a4 += wg * bf_lo(pw.z); a5 += wg * bf_hi(pw.z);            \
    a6 += wg * bf_lo(pw.w); a7 += wg * bf_hi(pw.w);            \
  }

__global__ __launch_bounds__(256) void k_agg1(const uint2* __restrict__ binned,
                                              const int* __restrict__ bb,
                                              const uint4* __restrict__ s1u4,
                                              const float* __restrict__ b1,
                                              uint4* __restrict__ h_u4,
                                              uint2* __restrict__ entries,
                                              int* __restrict__ row_start) {
  __shared__ uint2 se[STAGE_CAP];
  __shared__ int cnt[BKT_SIZE];
  __shared__ int sc[BKT_SIZE];
  __shared__ int cur[BKT_SIZE];
  __shared__ int rs[BKT_SIZE + 1];
  int t = threadIdx.x;
  int b = blockIdx.x;
  int beg = bb[b], end = bb[b + 1];
  int n = end - beg;
  bool fits = (n <= STAGE_CAP);
  if (t < BKT_SIZE) cnt[t] = 0;
  __syncthreads();
  if (fits) {
    // ---- single global pass: stage bucket edges into registers ----
    uint2 er[18];
#pragma unroll
    for (int k = 0; k < 18; ++k) {
      int idx = t + 256 * k;
      int cidx = idx < n ? idx : (n - 1);
      er[k] = binned[beg + cidx];
    }
#pragma unroll
    for (int k = 0; k < 18; ++k) {
      if (t + 256 * k < n) atomicAdd(&cnt[(er[k].x >> 20) & 127u], 1);
    }
    __syncthreads();
    if (t < BKT_SIZE) sc[t] = cnt[t];
    __syncthreads();
    for (int off = 1; off < BKT_SIZE; off <<= 1) {
      int add = (t < BKT_SIZE && t >= off) ? sc[t - off] : 0;
      __syncthreads();
      if (t < BKT_SIZE) sc[t] += add;
      __syncthreads();
    }
    if (t < BKT_SIZE) {
      int ex = sc[t] - cnt[t];
      rs[t] = ex; cur[t] = ex;
      int dstg = b * BKT_SIZE + t;
      if (dstg < N_NODES) row_start[dstg] = beg + ex;
    }
    if (t == 0) rs[BKT_SIZE] = n;
    __syncthreads();
#pragma unroll
    for (int k = 0; k < 18; ++k) {
      if (t + 256 * k < n) {
        int pos = atomicAdd(&cur[(er[k].x >> 20) & 127u], 1);
        se[pos] = er[k];
      }
    }
    __syncthreads();
    // coalesced writeback of sorted edges for k_agg2
    for (int i = t; i < n; i += 256) entries[beg + i] = se[i];
  } else {
    // never-expected fallback: unsorted copy + degenerate row_start
    if (t < BKT_SIZE) {
      int dstg = b * BKT_SIZE + t;
      if (dstg < N_NODES) row_start[dstg] = beg;
    }
    for (int i = t; i < n; i += 256) entries[beg + i] = binned[beg + i];
    __syncthreads();
  }

  int wid = t >> 6, lane = t & 63;
  int q = lane >> 4, sub = lane & 15;
  int base_r = b * BKT_SIZE;
  for (int dl = wid * 32; dl < wid * 32 + 32; ++dl) {
    int dst = base_r + dl;
    if (dst >= N_NODES) break;
    float a0 = 0.f, a1 = 0.f, a2 = 0.f, a3 = 0.f;
    float a4 = 0.f, a5 = 0.f, a6 = 0.f, a7 = 0.f;
    if (fits) {
      int i = rs[dl], send = rs[dl + 1];
      for (; i + 16 <= send; i += 16) {
        uint2 eA = se[i + q];
        uint2 eB = se[i + 4 + q];
        uint2 eC = se[i + 8 + q];
        uint2 eD = se[i + 12 + q];
        A1_EDGE(eA);
        A1_EDGE(eB);
        A1_EDGE(eC);
        A1_EDGE(eD);
      }
      for (; i + 8 <= send; i += 8) {
        uint2 eA = se[i + q];
        uint2 eB = se[i + 4 + q];
        A1_EDGE(eA);
        A1_EDGE(eB);
      }
      for (; i < send; i += 4) {
        int idx = i + q;
        bool ok = idx < send;
        uint2 eA = ok ? se[idx] : make_uint2(0u, 0u);
        u32 sA = eA.x & 0xFFFFFu;
        float wA = ok ? __uint_as_float(eA.y) : 0.f;
        uint4 pA = s1u4[(size_t)sA * 16 + sub];
        a0 += wA * bf_lo(pA.x); a1 += wA * bf_hi(pA.x);
        a2 += wA * bf_lo(pA.y); a3 += wA * bf_hi(pA.y);
        a4 += wA * bf_lo(pA.z); a5 += wA * bf_hi(pA.z);
        a6 += wA * bf_lo(pA.w); a7 += wA * bf_hi(pA.w);
      }
    } else {
      // never-expected fallback: masked scan of whole bucket from global
      for (int i = beg; i < end; i += 4) {
        int idx = i + q;
        bool ok = idx < end;
        uint2 eA = ok ? binned[idx] : make_uint2(0u, 0u);
        bool mine = ok && (((eA.x >> 20) & 127u) == (u32)dl);
        u32 sA = eA.x & 0xFFFFFu;
        float wA = mine ? __uint_as_float(eA.y) : 0.f;
        uint4 pA = s1u4[(size_t)sA * 16 + sub];
        a0 += wA * bf_lo(pA.x); a1 += wA * bf_hi(pA.x);
        a2 += wA * bf_lo(pA.y); a3 += wA * bf_hi(pA.y);
        a4 += wA * bf_lo(pA.z); a5 += wA * bf_hi(pA.z);
        a6 += wA * bf_lo(pA.w); a7 += wA * bf_hi(pA.w);
      }
    }
    a0 += __shfl_xor(a0, 16); a1 += __shfl_xor(a1, 16);
    a2 += __shfl_xor(a2, 16); a3 += __shfl_xor(a3, 16);
    a4 += __shfl_xor(a4, 16); a5 += __shfl_xor(a5, 16);
    a6 += __shfl_xor(a6, 16); a7 += __shfl_xor(a7, 16);
    a0 += __shfl_xor(a0, 32); a1 += __shfl_xor(a1, 32);
    a2 += __shfl_xor(a2, 32); a3 += __shfl_xor(a3, 32);
    a4 += __shfl_xor(a4, 32); a5 += __shfl_xor(a5, 32);
    a6 += __shfl_xor(a6, 32); a7 += __shfl_xor(a7, 32);
    if (q == 0) {
      f32x4 bL = *(const f32x4*)(b1 + 8 * sub);
      f32x4 bH = *(const f32x4*)(b1 + 8 * sub + 4);
      float h0 = fmaxf(a0 + bL[0], 0.f), h1 = fmaxf(a1 + bL[1], 0.f);
      float h2 = fmaxf(a2 + bL[2], 0.f), h3 = fmaxf(a3 + bL[3], 0.f);
      float h4 = fmaxf(a4 + bH[0], 0.f), h5 = fmaxf(a5 + bH[1], 0.f);
      float h6 = fmaxf(a6 + bH[2], 0.f), h7 = fmaxf(a7 + bH[3], 0.f);
      uint4 pk;
      pk.x = cvt_pk_bf16(h0, h1);
      pk.y = cvt_pk_bf16(h2, h3);
      pk.z = cvt_pk_bf16(h4, h5);
      pk.w = cvt_pk_bf16(h6, h7);
      h_u4[(size_t)dst * 16 + sub] = pk;
    }
  }
}

// ---------------- GEMM2: support2[N][40] bf16 = h @ W2 (vector fp32) -------
// 32 rows per block (4x fewer W2->LDS reloads than 8 rows/block).

__global__ __launch_bounds__(320) void k_gemm2(const u16* __restrict__ h,
                                               const float* __restrict__ W2,
                                               u16* __restrict__ s2) {
  __shared__ float w2s[128 * 40];
  for (int i = threadIdx.x; i < 128 * 40; i += 320) w2s[i] = W2[i];
  __syncthreads();
  int g = threadIdx.x / 40;        // 0..7
  int c = threadIdx.x % 40;
  int r0 = blockIdx.x * 32 + g;    // rows r0 + 8j, j=0..3
  const u32* hu = (const u32*)h;
  float acc0 = 0.f, acc1 = 0.f, acc2 = 0.f, acc3 = 0.f;
#pragma unroll 8
  for (int k2 = 0; k2 < 64; ++k2) {
    float wlo = w2s[(2 * k2) * 40 + c];
    float whi = w2s[(2 * k2 + 1) * 40 + c];
    u32 p0 = hu[(size_t)(r0)      * 64 + k2];
    u32 p1 = hu[(size_t)(r0 + 8)  * 64 + k2];
    u32 p2 = hu[(size_t)(r0 + 16) * 64 + k2];
    u32 p3 = hu[(size_t)(r0 + 24) * 64 + k2];
    acc0 += bf_lo(p0) * wlo + bf_hi(p0) * whi;
    acc1 += bf_lo(p1) * wlo + bf_hi(p1) * whi;
    acc2 += bf_lo(p2) * wlo + bf_hi(p2) * whi;
    acc3 += bf_lo(p3) * wlo + bf_hi(p3) * whi;
  }
  s2[(size_t)(r0)      * 40 + c] = f32_bf16(acc0);
  s2[(size_t)(r0 + 8)  * 40 + c] = f32_bf16(acc1);
  s2[(size_t)(r0 + 16) * 40 + c] = f32_bf16(acc2);
  s2[(size_t)(r0 + 24) * 40 + c] = f32_bf16(acc3);
}

// ---------------- layer-2 aggregate + bias + log_softmax -> out ------------
// one wave per dst from the CSR k_agg1 produced; 3 edges/pass, 12 in flight.

__global__ __launch_bounds__(256) void k_agg2(const uint2* __restrict__ entries,
                                              const int* __restrict__ row_start,
                                              const int* __restrict__ bb,
                                              const u32* __restrict__ s2u,
                                              const float* __restrict__ b2,
                                              float* __restrict__ out) {
  int wid = threadIdx.x >> 6, lane = threadIdx.x & 63;
  int dst = __builtin_amdgcn_readfirstlane(blockIdx.x * 4 + wid);
  if (dst >= N_NODES) return;
  int bkt = dst >> BKT_SHIFT;
  int bbeg = bb[bkt], bend = bb[bkt + 1];
  bool fits = (bend - bbeg) <= STAGE_CAP;
  u32 g = (u32)lane / 20u;
  u32 d = (u32)lane - 20u * g;
  float a0 = 0.f, a1 = 0.f;
  if (fits) {
    int beg = row_start[dst], end = row_start[dst + 1];
    int i = beg;
    for (; i + 12 <= end; i += 12) {
      uint2 e0 = entries[i],     e1 = entries[i + 1],  e2 = entries[i + 2];
      uint2 e3 = entries[i + 3], e4 = entries[i + 4],  e5 = entries[i + 5];
      uint2 e6 = entries[i + 6], e7 = entries[i + 7],  e8 = entries[i + 8];
      uint2 e9 = entries[i + 9], ea = entries[i + 10], eb = entries[i + 11];
      uint2 A = (g == 1) ? e1 : ((g == 2) ? e2 : e0);
      uint2 B = (g == 1) ? e4 : ((g == 2) ? e5 : e3);
      uint2 C = (g == 1) ? e7 : ((g == 2) ? e8 : e6);
      uint2 D = (g == 1) ? ea : ((g == 2) ? eb : e9);
      u32 sA = A.x & 0xFFFFFu, sB = B.x & 0xFFFFFu;
      u32 sC = C.x & 0xFFFFFu, sD = D.x & 0xFFFFFu;
      float wA = __uint_as_float(A.y), wB = __uint_as_float(B.y);
      float wC = __uint_as_float(C.y), wD = __uint_as_float(D.y);
      u32 pA = s2u[(size_t)sA * 20 + d];
      u32 pB = s2u[(size_t)sB * 20 + d];
      u32 pC = s2u[(size_t)sC * 20 + d];
      u32 pD = s2u[(size_t)sD * 20 + d];
      a0 += wA * bf_lo(pA); a1 += wA * bf_hi(pA);
      a0 += wB * bf_lo(pB); a1 += wB * bf_hi(pB);
      a0 += wC * bf_lo(pC); a1 += wC * bf_hi(pC);
      a0 += wD * bf_lo(pD); a1 += wD * bf_hi(pD);
    }
    for (; i + 6 <= end; i += 6) {
      uint2 e0 = entries[i],     e1 = entries[i + 1], e2 = entries[i + 2];
      uint2 e3 = entries[i + 3], e4 = entries[i + 4], e5 = entries[i + 5];
      uint2 A = (g == 1) ? e1 : ((g == 2) ? e2 : e0);
      uint2 B = (g == 1) ? e4 : ((g == 2) ? e5 : e3);
      u32 sA = A.x & 0xFFFFFu;
      u32 sB = B.x & 0xFFFFFu;
      float wA = __uint_as_float(A.y), wB = __uint_as_float(B.y);
      u32 pA = s2u[(size_t)sA * 20 + d];
      u32 pB = s2u[(size_t)sB * 20 + d];
      a0 += wA * bf_lo(pA); a1 += wA * bf_hi(pA);
      a0 += wB * bf_lo(pB); a1 += wB * bf_hi(pB);
    }
    for (; i < end; i += 3) {
      uint2 e0 = entries[i];
      uint2 e1 = (i + 1 < end) ? entries[i + 1] : make_uint2(e0.x, 0u);
      uint2 e2 = (i + 2 < end) ? entries[i + 2] : make_uint2(e0.x, 0u);
      uint2 A = (g == 1) ? e1 : ((g == 2) ? e2 : e0);
      u32 sA = A.x & 0xFFFFFu;
      float wA = __uint_as_float(A.y);
      u32 pA = s2u[(size_t)sA * 20 + d];
      a0 += wA * bf_lo(pA); a1 += wA * bf_hi(pA);
    }
  } else {
    // never-expected fallback: masked scan of whole (unsorted) bucket
    u32 dl = (u32)(dst & (BKT_SIZE - 1));
    for (int i = bbeg; i < bend; i += 3) {
      uint2 e0 = entries[i];
      uint2 e1 = (i + 1 < bend) ? entries[i + 1] : make_uint2(0u, 0u);
      uint2 e2 = (i + 2 < bend) ? entries[i + 2] : make_uint2(0u, 0u);
      uint2 A = (g == 1) ? e1 : ((g == 2) ? e2 : e0);
      bool mine = (((A.x >> 20) & 127u) == dl);
      u32 sA = A.x & 0xFFFFFu;
      float wA = mine ? __uint_as_float(A.y) : 0.f;
      u32 pA = s2u[(size_t)sA * 20 + d];
      a0 += wA * bf_lo(pA); a1 += wA * bf_hi(pA);
    }
  }
  a0 += __shfl(a0, lane + 20) + __shfl(a0, lane + 40);
  a1 += __shfl(a1, lane + 20) + __shfl(a1, lane + 40);
  bool act = lane < 20;
  float v0 = -INFINITY, v1 = -INFINITY;
  if (act) {
    float2 bb2 = *(const float2*)(b2 + 2 * d);
    v0 = a0 + bb2.x;
    v1 = a1 + bb2.y;
  }
  float mx = fmaxf(v0, v1);
#pragma unroll
  for (int off = 16; off > 0; off >>= 1) mx = fmaxf(mx, __shfl_xor(mx, off));
  float e = act ? (__expf(v0 - mx) + __expf(v1 - mx)) : 0.f;
#pragma unroll
  for (int off = 16; off > 0; off >>= 1) e += __shfl_xor(e, off);
  if (act) {
    float ls = __logf(e);
    float2 o = make_float2((v0 - mx) - ls, (v1 - mx) - ls);
    *(float2*)(out + (size_t)dst * 40 + 2 * d) = o;
  }
}

// ---------------- launch ----------------

extern "C" void kernel_launch(void* const* d_in, const int* in_sizes, int n_in,
                              void* d_out, int out_size, void* d_ws, size_t ws_size,
                              hipStream_t stream) {
  const float* x = (const float*)d_in[0];
  const int* ei = (const int*)d_in[1];     // int32 [2][E]
  const float* ew = (const float*)d_in[2];
  const float* W1 = (const float*)d_in[3];
  const float* b1 = (const float*)d_in[4];
  const float* W2 = (const float*)d_in[5];
  const float* b2 = (const float*)d_in[6];
  float* out = (float*)d_out;
  const int* eis = ei;             // src row
  const int* eid = ei + N_EDGES;   // dst row

  char* p = (char*)d_ws;
  u16* w1t = (u16*)p;           p += 128 * 512 * 2;                 // 128 KiB
  int* ghist = (int*)p;         p += 1024 * 4;
  int* bb = (int*)p;            p += 1024 * 4;
  int* gcur = (int*)p;          p += 1024 * 4;
  int* row_start = (int*)p;     p += 100352 * 4;
  uint2* binned = (uint2*)p;    p += (size_t)N_EDGES * 8;           // 25.6 MB (live thru k_agg1)
  uint2* entries = (uint2*)p;   p += (size_t)N_EDGES * 8;           // 25.6 MB (written by k_agg1)
  u16* h = (u16*)p;             p += (size_t)N_NODES * 128 * 2;     // 25.6 MB
  u16* s1 = (u16*)p;            p += (size_t)N_NODES * 128 * 2;     // 25.6 MB
  u16* s2 = s1;                 // s1 dead after k_agg1; alias

  const int nchunk = (N_EDGES + CHUNK - 1) / CHUNK;  // 782
  k_w1t<<<(512 * 128) / 256, 256, 0, stream>>>(W1, w1t);
  k_zero2<<<1, 1024, 0, stream>>>(ghist);
  k_hist<<<nchunk, 256, 0, stream>>>(eid, ghist);
  k_base<<<1, 1024, 0, stream>>>(ghist, bb, gcur, row_start);
  k_bin<<<nchunk, 256, 0, stream>>>(eis, eid, ew, gcur, binned);
  k_gemm1<<<(N_NODES + 127) / 128, 256, 0, stream>>>(x, w1t, s1);
  k_agg1<<<N_BKT, 256, 0, stream>>>(binned, bb, (const uint4*)s1, b1, (uint4*)h,
                                    entries, row_start);
  k_gemm2<<<N_NODES / 32, 320, 0, stream>>>(h, W2, s2);
  k_agg2<<<N_NODES / 4, 256, 0, stream>>>(entries, row_start, bb, (const u32*)s2, b2, out);
}